// Round 1
// baseline (379.145 us; speedup 1.0000x reference)
//
#include <hip/hip_runtime.h>

#define L2E 1.4426950408889634f

// ---------------- Wsum: wsum[h] = sum_n W[h][n] ----------------
__global__ __launch_bounds__(256) void wsum_kernel(const float* __restrict__ W,
                                                   float* __restrict__ wsum) {
    int wave = threadIdx.x >> 6, lane = threadIdx.x & 63;
    int h = blockIdx.x * 4 + wave;            // grid 64 -> h in [0,256)
    const float* row = W + (size_t)h * 1024;
    float s = 0.f;
#pragma unroll
    for (int i = 0; i < 16; ++i) s += row[lane + 64 * i];
#pragma unroll
    for (int off = 32; off; off >>= 1) s += __shfl_xor(s, off, 64);
    if (lane == 0) wsum[h] = s;
}

// ---------------- GEMM: C[8192,256] = X[8192,1024] @ W[256,1024]^T ----------
// rows of C alternate: row 2b = values, row 2b+1 = mask
#define BM 64
#define BN 64
#define BK 16
#define LDT 68   // padded leading dim (17*16B rows -> 16B-aligned, 2-way max bank alias)

__global__ __launch_bounds__(256) void gemm_kernel(const float* __restrict__ X,
                                                   const float* __restrict__ W,
                                                   float* __restrict__ C) {
    __shared__ float As[BK][LDT];
    __shared__ float Bs[BK][LDT];
    const int tid = threadIdx.x;
    const int row = tid >> 2;          // 0..63
    const int c4  = (tid & 3) << 2;    // 0,4,8,12
    const int gm0 = blockIdx.x * BM;
    const int gn0 = blockIdx.y * BN;
    const int tx = tid & 15, ty = tid >> 4;
    float acc[4][4] = {};
    const float* Xp = X + (size_t)(gm0 + row) * 1024 + c4;
    const float* Wp = W + (size_t)(gn0 + row) * 1024 + c4;

    for (int kt = 0; kt < 1024; kt += BK) {
        float4 a = *(const float4*)(Xp + kt);
        float4 b = *(const float4*)(Wp + kt);
        __syncthreads();
        As[c4 + 0][row] = a.x; As[c4 + 1][row] = a.y;
        As[c4 + 2][row] = a.z; As[c4 + 3][row] = a.w;
        Bs[c4 + 0][row] = b.x; Bs[c4 + 1][row] = b.y;
        Bs[c4 + 2][row] = b.z; Bs[c4 + 3][row] = b.w;
        __syncthreads();
#pragma unroll
        for (int kk = 0; kk < BK; ++kk) {
            float4 av = *(const float4*)&As[kk][ty << 2];
            float4 bv = *(const float4*)&Bs[kk][tx << 2];
            float am[4] = {av.x, av.y, av.z, av.w};
            float bn[4] = {bv.x, bv.y, bv.z, bv.w};
#pragma unroll
            for (int i = 0; i < 4; ++i)
#pragma unroll
                for (int j = 0; j < 4; ++j)
                    acc[i][j] = __builtin_fmaf(am[i], bn[j], acc[i][j]);
        }
    }
#pragma unroll
    for (int i = 0; i < 4; ++i) {
        float4 o = {acc[i][0], acc[i][1], acc[i][2], acc[i][3]};
        *(float4*)(C + (size_t)(gm0 + (ty << 2) + i) * 256 + gn0 + (tx << 2)) = o;
    }
}

// ---------------- Head: per (b,k) row softmax-dot -----------------
__global__ __launch_bounds__(256) void head_kernel(const float* __restrict__ C,
                                                   const float* __restrict__ wsum,
                                                   const float* __restrict__ cov,
                                                   const float* __restrict__ ld,
                                                   float* __restrict__ out) {
    const int wave = threadIdx.x >> 6, lane = threadIdx.x & 63;
    const int b = blockIdx.x * 4 + wave;       // grid 1024 -> b in [0,4096)
    const float* valr = C + (size_t)(2 * b) * 256;
    const float* mskr = valr + 256;
    const int j0 = lane << 2;

    float4 v4 = *(const float4*)(valr + j0);
    float4 m4 = *(const float4*)(mskr + j0);
    float4 s4 = *(const float4*)(wsum + j0);
    float om[4] = {s4.x - m4.x, s4.y - m4.y, s4.z - m4.z, s4.w - m4.w};
    float va[4] = {v4.x, v4.y, v4.z, v4.w};
    float* outr = out + (size_t)b * 256;

    for (int k = 0; k < 256; ++k) {
        float mk = mskr[k];
        float4 c4 = *(const float4*)(cov + (size_t)k * 256 + j0);
        float4 l4 = *(const float4*)(ld + (size_t)k * 256 + j0);
        float cj[4] = {c4.x, c4.y, c4.z, c4.w};
        float lj[4] = {l4.x, l4.y, l4.z, l4.w};
        float r[4];
#pragma unroll
        for (int i = 0; i < 4; ++i)
            r[i] = __builtin_fmaf(mk, cj[i] * om[i], (j0 + i) == k ? 1.f : 0.f);

        float s = (r[0] + r[1]) + (r[2] + r[3]);
#pragma unroll
        for (int off = 32; off; off >>= 1) s += __shfl_xor(s, off, 64);
        float inv = __builtin_amdgcn_rcpf(s);

        float w[4];
#pragma unroll
        for (int i = 0; i < 4; ++i) w[i] = r[i] * inv;
        float mx = fmaxf(fmaxf(w[0], w[1]), fmaxf(w[2], w[3]));
#pragma unroll
        for (int off = 32; off; off >>= 1) mx = fmaxf(mx, __shfl_xor(mx, off, 64));

        float a = mx * L2E;
        float e[4];
#pragma unroll
        for (int i = 0; i < 4; ++i) e[i] = exp2f(__builtin_fmaf(w[i], L2E, -a));

        float se = (e[0] + e[1]) + (e[2] + e[3]);
        float dp = e[0] * (lj[0] * va[0]);
#pragma unroll
        for (int i = 1; i < 4; ++i) dp = __builtin_fmaf(e[i], lj[i] * va[i], dp);
#pragma unroll
        for (int off = 32; off; off >>= 1) {
            se += __shfl_xor(se, off, 64);
            dp += __shfl_xor(dp, off, 64);
        }
        if (lane == 0) outr[k] = dp * __builtin_amdgcn_rcpf(se);
    }
}

extern "C" void kernel_launch(void* const* d_in, const int* in_sizes, int n_in,
                              void* d_out, int out_size, void* d_ws, size_t ws_size,
                              hipStream_t stream) {
    const float* x    = (const float*)d_in[0];   // [4096,2,1024]
    const float* W    = (const float*)d_in[1];   // [256,1024]
    const float* cov  = (const float*)d_in[2];   // [256,256]
    const float* ldng = (const float*)d_in[3];   // [256,256]
    float* out = (float*)d_out;                  // [4096,256]

    float* C    = (float*)d_ws;                  // [8192,256]
    float* wsum = C + (size_t)8192 * 256;        // [256]

    wsum_kernel<<<64, 256, 0, stream>>>(W, wsum);
    gemm_kernel<<<dim3(128, 4), 256, 0, stream>>>(x, W, C);
    head_kernel<<<1024, 256, 0, stream>>>(C, wsum, cov, ldng, out);
}

// Round 3
// 209.808 us; speedup vs baseline: 1.8071x; 1.8071x over previous
//
#include <hip/hip_runtime.h>

#define L2E 1.4426950408889634f

// ---------------- Wsum: wsum[h] = sum_n W[h][n] ----------------
__global__ __launch_bounds__(256) void wsum_kernel(const float* __restrict__ W,
                                                   float* __restrict__ wsum) {
    int wave = threadIdx.x >> 6, lane = threadIdx.x & 63;
    int h = blockIdx.x * 4 + wave;            // grid 64 -> h in [0,256)
    const float* row = W + (size_t)h * 1024;
    float s = 0.f;
#pragma unroll
    for (int i = 0; i < 16; ++i) s += row[lane + 64 * i];
#pragma unroll
    for (int off = 32; off; off >>= 1) s += __shfl_xor(s, off, 64);
    if (lane == 0) wsum[h] = s;
}

// ---------------- 256x256 transpose (cov -> covT, ld -> ldT) ----------------
__global__ __launch_bounds__(256) void transpose_kernel(const float* __restrict__ in,
                                                        float* __restrict__ outT) {
    __shared__ float t[32][33];
    const int bx = blockIdx.x * 32, by = blockIdx.y * 32;
    const int x = threadIdx.x & 31;
    const int y = threadIdx.x >> 5;           // 0..7
#pragma unroll
    for (int i = 0; i < 32; i += 8)
        t[y + i][x] = in[(size_t)(by + y + i) * 256 + bx + x];
    __syncthreads();
#pragma unroll
    for (int i = 0; i < 32; i += 8)
        outT[(size_t)(bx + y + i) * 256 + by + x] = t[x][y + i];
}

// ---------------- GEMM: C[8192,256] = X[8192,1024] @ W[256,1024]^T ----------
// rows of C alternate: row 2b = values, row 2b+1 = mask
#define BM 64
#define BN 64
#define BK 16
#define LDT 68

__global__ __launch_bounds__(256) void gemm_kernel(const float* __restrict__ X,
                                                   const float* __restrict__ W,
                                                   float* __restrict__ C) {
    __shared__ float As[BK][LDT];
    __shared__ float Bs[BK][LDT];
    const int tid = threadIdx.x;
    const int row = tid >> 2;
    const int c4  = (tid & 3) << 2;
    const int gm0 = blockIdx.x * BM;
    const int gn0 = blockIdx.y * BN;
    const int tx = tid & 15, ty = tid >> 4;
    float acc[4][4] = {};
    const float* Xp = X + (size_t)(gm0 + row) * 1024 + c4;
    const float* Wp = W + (size_t)(gn0 + row) * 1024 + c4;

    for (int kt = 0; kt < 1024; kt += BK) {
        float4 a = *(const float4*)(Xp + kt);
        float4 b = *(const float4*)(Wp + kt);
        __syncthreads();
        As[c4 + 0][row] = a.x; As[c4 + 1][row] = a.y;
        As[c4 + 2][row] = a.z; As[c4 + 3][row] = a.w;
        Bs[c4 + 0][row] = b.x; Bs[c4 + 1][row] = b.y;
        Bs[c4 + 2][row] = b.z; Bs[c4 + 3][row] = b.w;
        __syncthreads();
#pragma unroll
        for (int kk = 0; kk < BK; ++kk) {
            float4 av = *(const float4*)&As[kk][ty << 2];
            float4 bv = *(const float4*)&Bs[kk][tx << 2];
            float am[4] = {av.x, av.y, av.z, av.w};
            float bn[4] = {bv.x, bv.y, bv.z, bv.w};
#pragma unroll
            for (int i = 0; i < 4; ++i)
#pragma unroll
                for (int j = 0; j < 4; ++j)
                    acc[i][j] = __builtin_fmaf(am[i], bn[j], acc[i][j]);
        }
    }
#pragma unroll
    for (int i = 0; i < 4; ++i) {
        float4 o = {acc[i][0], acc[i][1], acc[i][2], acc[i][3]};
        *(float4*)(C + (size_t)(gm0 + (ty << 2) + i) * 256 + gn0 + (tx << 2)) = o;
    }
}

// ---------------- Head: thread-per-(b,k), two register passes over j --------
// r_j = delta_kj + mk * p_j,  p_j = cov[k][j] * omm[b][j]
// pass1: sp = sum_all_j p;  pmax/pmin over j != k;  rkk = 1 + mk*p_kk folded in.
// mx bounds EXACTLY the corrected distribution -> argmax exp ~ 1, se >= 1.
// pass2: exponent selected per element: diag j==k uses argk, else fma(p,c1,c0).
#define NB 4

__global__ __launch_bounds__(256) void head_kernel(const float* __restrict__ C,
                                                   const float* __restrict__ wsum,
                                                   const float* __restrict__ covT,
                                                   const float* __restrict__ ldT,
                                                   const float* __restrict__ cov,
                                                   float* __restrict__ out) {
    __shared__ float2 pv[NB][256];            // {omm, values}
    const int k = threadIdx.x;
    const int b0 = blockIdx.x * NB;

    const float ws = wsum[k];
    const float cdiag = cov[(size_t)k * 257];

    float mk[NB], sp[NB], pmax[NB], pmin[NB];
#pragma unroll
    for (int b = 0; b < NB; ++b) {
        float va = C[(size_t)(2 * (b0 + b)) * 256 + k];
        float ms = C[(size_t)(2 * (b0 + b) + 1) * 256 + k];
        mk[b] = ms;
        pv[b][k] = make_float2(ws - ms, va);
        sp[b] = 0.f; pmax[b] = -INFINITY; pmin[b] = INFINITY;
    }
    __syncthreads();

    // ---- pass 1: full row sum of p; extrema over off-diagonal only ----
#pragma unroll 4
    for (int j = 0; j < 256; ++j) {
        float cv = covT[j * 256 + k];
        const bool diag = (j == k);
#pragma unroll
        for (int b = 0; b < NB; ++b) {
            float p = cv * pv[b][j].x;
            sp[b] += p;
            pmax[b] = fmaxf(pmax[b], diag ? -3.0e38f : p);
            pmin[b] = fminf(pmin[b], diag ?  3.0e38f : p);
        }
    }

    // ---- per-b constants (corrected-distribution max bound) ----
    float c1[NB], c0[NB], argk[NB], se[NB], dp[NB];
#pragma unroll
    for (int b = 0; b < NB; ++b) {
        float m   = mk[b];
        float omk = pv[b][k].x;
        float pkk = cdiag * omk;                       // uncorrected p at j==k
        float rkk = __builtin_fmaf(m, pkk, 1.0f);      // corrected r at j==k
        float sum = __builtin_fmaf(m, sp[b], 1.0f);    // +1 from the delta
        float iv  = __builtin_amdgcn_rcpf(sum);
        float rmax = (m >= 0.f) ? m * pmax[b] : m * pmin[b];  // off-diag r max
        float rmin = (m >= 0.f) ? m * pmin[b] : m * pmax[b];  // off-diag r min
        rmax = fmaxf(rmax, rkk);
        rmin = fminf(rmin, rkk);
        float mx = (iv >= 0.f) ? iv * rmax : iv * rmin;       // == max_j w_j
        c1[b]   = m * iv * L2E;
        c0[b]   = -mx * L2E;
        argk[b] = __builtin_fmaf(rkk * iv, L2E, c0[b]);       // diag exponent
        se[b]   = 0.f; dp[b] = 0.f;
    }

    // ---- pass 2: exp + weighted dot (diag exponent selected in-loop) ----
#pragma unroll 4
    for (int j = 0; j < 256; ++j) {
        float cv = covT[j * 256 + k];
        float lv = ldT[j * 256 + k];
        const bool diag = (j == k);
#pragma unroll
        for (int b = 0; b < NB; ++b) {
            float2 ov = pv[b][j];
            float p = cv * ov.x;
            float arg = __builtin_fmaf(p, c1[b], c0[b]);
            arg = diag ? argk[b] : arg;
            float e = __builtin_amdgcn_exp2f(arg);
            se[b] += e;
            dp[b]  = __builtin_fmaf(e, lv * ov.y, dp[b]);
        }
    }

#pragma unroll
    for (int b = 0; b < NB; ++b)
        out[(size_t)(b0 + b) * 256 + k] = dp[b] * __builtin_amdgcn_rcpf(se[b]);
}

extern "C" void kernel_launch(void* const* d_in, const int* in_sizes, int n_in,
                              void* d_out, int out_size, void* d_ws, size_t ws_size,
                              hipStream_t stream) {
    const float* x    = (const float*)d_in[0];   // [4096,2,1024]
    const float* W    = (const float*)d_in[1];   // [256,1024]
    const float* cov  = (const float*)d_in[2];   // [256,256]
    const float* ldng = (const float*)d_in[3];   // [256,256]
    float* out = (float*)d_out;                  // [4096,256]

    float* C    = (float*)d_ws;                  // [8192,256]
    float* wsum = C + (size_t)8192 * 256;        // [256]
    float* covT = wsum + 256;                    // [256,256]
    float* ldT  = covT + 65536;                  // [256,256]

    wsum_kernel<<<64, 256, 0, stream>>>(W, wsum);
    transpose_kernel<<<dim3(8, 8), 256, 0, stream>>>(cov, covT);
    transpose_kernel<<<dim3(8, 8), 256, 0, stream>>>(ldng, ldT);
    gemm_kernel<<<dim3(128, 4), 256, 0, stream>>>(x, W, C);
    head_kernel<<<1024, 256, 0, stream>>>(C, wsum, covT, ldT, cov, out);
}

// Round 5
// 149.914 us; speedup vs baseline: 2.5291x; 1.3995x over previous
//
#include <hip/hip_runtime.h>

#define L2E 1.4426950408889634f

// ---------------- Wsum: wsum[h] = sum_n W[h][n] ----------------
__global__ __launch_bounds__(256) void wsum_kernel(const float* __restrict__ W,
                                                   float* __restrict__ wsum) {
    int wave = threadIdx.x >> 6, lane = threadIdx.x & 63;
    int h = blockIdx.x * 4 + wave;            // grid 64 -> h in [0,256)
    const float* row = W + (size_t)h * 1024;
    float s = 0.f;
#pragma unroll
    for (int i = 0; i < 16; ++i) s += row[lane + 64 * i];
#pragma unroll
    for (int off = 32; off; off >>= 1) s += __shfl_xor(s, off, 64);
    if (lane == 0) wsum[h] = s;
}

// ------- prep: covT0[j][k] = cov[k][j] (diag->0); clT[j][k] = {cov0, ld0} ----
__global__ __launch_bounds__(256) void prep_kernel(const float* __restrict__ cov,
                                                   const float* __restrict__ ld,
                                                   float* __restrict__ covT0,
                                                   float2* __restrict__ clT) {
    __shared__ float tc[32][33];
    __shared__ float tl[32][33];
    const int bx = blockIdx.x * 32, by = blockIdx.y * 32;
    const int x = threadIdx.x & 31;
    const int y = threadIdx.x >> 5;           // 0..7
#pragma unroll
    for (int i = 0; i < 32; i += 8) {
        int r = by + y + i, c = bx + x;
        float cv = cov[(size_t)r * 256 + c];
        float lv = ld[(size_t)r * 256 + c];
        if (r == c) { cv = 0.f; lv = 0.f; }
        tc[y + i][x] = cv; tl[y + i][x] = lv;
    }
    __syncthreads();
#pragma unroll
    for (int i = 0; i < 32; i += 8) {
        int r = bx + y + i, c = by + x;
        float cv = tc[x][y + i], lv = tl[x][y + i];
        covT0[(size_t)r * 256 + c] = cv;
        clT[(size_t)r * 256 + c] = make_float2(cv, lv);
    }
}

// ---------------- GEMM: C[8192,256] = X[8192,1024] @ W[256,1024]^T ----------
// rows of C alternate: row 2b = values, row 2b+1 = mask
#define BM 64
#define BN 64
#define BK 16
#define LDT 68

__global__ __launch_bounds__(256) void gemm_kernel(const float* __restrict__ X,
                                                   const float* __restrict__ W,
                                                   float* __restrict__ C) {
    __shared__ float As[BK][LDT];
    __shared__ float Bs[BK][LDT];
    const int tid = threadIdx.x;
    const int row = tid >> 2;
    const int c4  = (tid & 3) << 2;
    const int gm0 = blockIdx.x * BM;
    const int gn0 = blockIdx.y * BN;
    const int tx = tid & 15, ty = tid >> 4;
    float acc[4][4] = {};
    const float* Xp = X + (size_t)(gm0 + row) * 1024 + c4;
    const float* Wp = W + (size_t)(gn0 + row) * 1024 + c4;

    float4 a = *(const float4*)(Xp);
    float4 b = *(const float4*)(Wp);
    for (int kt = 0; kt < 1024; kt += BK) {
        __syncthreads();
        As[c4 + 0][row] = a.x; As[c4 + 1][row] = a.y;
        As[c4 + 2][row] = a.z; As[c4 + 3][row] = a.w;
        Bs[c4 + 0][row] = b.x; Bs[c4 + 1][row] = b.y;
        Bs[c4 + 2][row] = b.z; Bs[c4 + 3][row] = b.w;
        __syncthreads();
        if (kt + BK < 1024) {                 // prefetch next tile into regs
            a = *(const float4*)(Xp + kt + BK);
            b = *(const float4*)(Wp + kt + BK);
        }
#pragma unroll
        for (int kk = 0; kk < BK; ++kk) {
            float4 av = *(const float4*)&As[kk][ty << 2];
            float4 bv = *(const float4*)&Bs[kk][tx << 2];
            float am[4] = {av.x, av.y, av.z, av.w};
            float bn[4] = {bv.x, bv.y, bv.z, bv.w};
#pragma unroll
            for (int i = 0; i < 4; ++i)
#pragma unroll
                for (int j = 0; j < 4; ++j)
                    acc[i][j] = __builtin_fmaf(am[i], bn[j], acc[i][j]);
        }
    }
#pragma unroll
    for (int i = 0; i < 4; ++i) {
        float4 o = {acc[i][0], acc[i][1], acc[i][2], acc[i][3]};
        *(float4*)(C + (size_t)(gm0 + (ty << 2) + i) * 256 + gn0 + (tx << 2)) = o;
    }
}

// ---------------- Head: thread-per-(b,k), zero-diag operands ----------------
// off-diag r_j = mk * p_j, p_j = cov0[k][j]*omm[b][j];  r_kk = 1 + mk*p_kk.
// pass1 (cov0): sp = sum_{j!=k} p; pmax/pmin over p (spurious 0 candidate is
// safe: sum_j w_j = 1 => max w >= 1/256 > 0).  mx = exact max of corrected w.
// pass2 (cov0,ld0): e = exp2(fma(p,c1,c0)); diag contributes exp2(c0) to se
// (subtracted in epilogue) and 0 to dp (ld diag zeroed).
#define NB 4

__global__ __launch_bounds__(256) void head_kernel(const float* __restrict__ C,
                                                   const float* __restrict__ wsum,
                                                   const float* __restrict__ covT0,
                                                   const float2* __restrict__ clT,
                                                   const float* __restrict__ cov,
                                                   const float* __restrict__ ld,
                                                   float* __restrict__ out) {
    __shared__ float  omm[NB][256];
    __shared__ float2 pv[NB][256];            // {omm, values}
    const int k = threadIdx.x;
    const int b0 = blockIdx.x * NB;

    const float ws = wsum[k];
    const float cdiag = cov[(size_t)k * 257];
    const float ldiag = ld[(size_t)k * 257];

    float mk[NB], vak[NB], omk[NB], sp[NB], pmax[NB], pmin[NB];
#pragma unroll
    for (int b = 0; b < NB; ++b) {
        float va = C[(size_t)(2 * (b0 + b)) * 256 + k];
        float ms = C[(size_t)(2 * (b0 + b) + 1) * 256 + k];
        float o  = ws - ms;
        mk[b] = ms; vak[b] = va; omk[b] = o;
        omm[b][k] = o;
        pv[b][k] = make_float2(o, va);
        sp[b] = 0.f; pmax[b] = 0.f; pmin[b] = 0.f;
    }
    __syncthreads();

    // ---- pass 1: off-diag row sum + extrema of p (no branches) ----
#pragma unroll 8
    for (int j = 0; j < 256; ++j) {
        float cv = covT0[j * 256 + k];
#pragma unroll
        for (int b = 0; b < NB; ++b) {
            float p = cv * omm[b][j];
            sp[b]   += p;
            pmax[b]  = fmaxf(pmax[b], p);
            pmin[b]  = fminf(pmin[b], p);
        }
    }

    // ---- per-b softmax constants (exact corrected max) ----
    float c1[NB], c0[NB], ek[NB], se[NB], dp[NB];
#pragma unroll
    for (int b = 0; b < NB; ++b) {
        float m   = mk[b];
        float pkk = cdiag * omk[b];
        float rkk = __builtin_fmaf(m, pkk, 1.0f);
        float sum = __builtin_fmaf(m, sp[b] + pkk, 1.0f);
        float iv  = __builtin_amdgcn_rcpf(sum);
        float rmax = (m >= 0.f) ? m * pmax[b] : m * pmin[b];
        float rmin = (m >= 0.f) ? m * pmin[b] : m * pmax[b];
        rmax = fmaxf(rmax, rkk);
        rmin = fminf(rmin, rkk);
        float mx = (iv >= 0.f) ? iv * rmax : iv * rmin;   // == max_j w_j
        c1[b] = m * iv * L2E;
        c0[b] = -mx * L2E;
        ek[b] = __builtin_amdgcn_exp2f(__builtin_fmaf(rkk * iv, L2E, c0[b]));
        se[b] = 0.f; dp[b] = 0.f;
    }

    // ---- pass 2: exp + weighted dot over zero-diag arrays ----
#pragma unroll 8
    for (int j = 0; j < 256; ++j) {
        float2 cl = clT[j * 256 + k];
#pragma unroll
        for (int b = 0; b < NB; ++b) {
            float2 ov = pv[b][j];
            float p = cl.x * ov.x;
            float e = __builtin_amdgcn_exp2f(__builtin_fmaf(p, c1[b], c0[b]));
            se[b] += e;
            dp[b]  = __builtin_fmaf(e, cl.y * ov.y, dp[b]);
        }
    }

    // ---- epilogue: swap spurious diag exp for the true one ----
#pragma unroll
    for (int b = 0; b < NB; ++b) {
        float espur = __builtin_amdgcn_exp2f(c0[b]);
        float sef = se[b] + (ek[b] - espur);
        float dpf = __builtin_fmaf(ek[b], ldiag * vak[b], dp[b]);
        out[(size_t)(b0 + b) * 256 + k] = dpf * __builtin_amdgcn_rcpf(sef);
    }
}

extern "C" void kernel_launch(void* const* d_in, const int* in_sizes, int n_in,
                              void* d_out, int out_size, void* d_ws, size_t ws_size,
                              hipStream_t stream) {
    const float* x    = (const float*)d_in[0];   // [4096,2,1024]
    const float* W    = (const float*)d_in[1];   // [256,1024]
    const float* cov  = (const float*)d_in[2];   // [256,256]
    const float* ldng = (const float*)d_in[3];   // [256,256]
    float* out = (float*)d_out;                  // [4096,256]

    float*  C     = (float*)d_ws;                        // [8192,256]
    float*  wsum  = C + (size_t)8192 * 256;              // [256]
    float*  covT0 = wsum + 256;                          // [256,256], diag 0
    float2* clT   = (float2*)(covT0 + 65536);            // [256,256] {cov0,ld0}

    wsum_kernel<<<64, 256, 0, stream>>>(W, wsum);
    prep_kernel<<<dim3(8, 8), 256, 0, stream>>>(cov, ldng, covT0, clT);
    gemm_kernel<<<dim3(128, 4), 256, 0, stream>>>(x, W, C);
    head_kernel<<<1024, 256, 0, stream>>>(C, wsum, covT0, clT, cov, ldng, out);
}